// Round 10
// baseline (34.006 us; speedup 1.0000x reference)
//
#include <hip/hip_runtime.h>
#include <hip/hip_bf16.h>
#include <math.h>
#include <stdint.h>

namespace {

typedef __bf16 bf16x8 __attribute__((ext_vector_type(8)));
typedef float f32x4 __attribute__((ext_vector_type(4)));

constexpr int L = 64;
constexpr int DH = 64;

// Swizzle key: distinct across BOTH stride-1 and stride-4 row sequences.
__device__ __forceinline__ int kkey(int r) { return (r ^ (r >> 2)) & 7; }
// bf16 tile (vt, cs): byte offset of (row,col), 128B rows, 16B-slot XOR.
__device__ __forceinline__ int swz(int row, int col) {
  return row * 128 + ((((col >> 3) ^ kkey(row)) & 7) << 4) + (col & 7) * 2;
}

__device__ __forceinline__ unsigned short bfbits(float f) {
  __bf16 h = (__bf16)f;
  return __builtin_bit_cast(unsigned short, h);
}
__device__ __forceinline__ __bf16 tobf(float f) { return (__bf16)f; }
__device__ __forceinline__ unsigned long long pack4(float a, float b, float c,
                                                    float d) {
  return (unsigned long long)bfbits(a) | ((unsigned long long)bfbits(b) << 16) |
         ((unsigned long long)bfbits(c) << 32) |
         ((unsigned long long)bfbits(d) << 48);
}

// Direct global->LDS DMA, 16B per lane. LDS dest = uniform base + lane*16.
__device__ __forceinline__ void gload16(const float* gsrc, float* ldst) {
  __builtin_amdgcn_global_load_lds(
      (const __attribute__((address_space(1))) uint32_t*)gsrc,
      (__attribute__((address_space(3))) uint32_t*)ldst, 16, 0, 0);
}

// One wave = one 64x64 chunk. vs R8: Q,K staged fp32 via global_load_lds
// (no dest VGPRs -> the compiler's load-sinking cannot serialize them; one
// vmcnt drain for all 32 DMA loads). Source addresses pre-swizzled so the
// linear LDS write lands XOR-swizzled (m173/m104 pattern).
__global__ __launch_bounds__(64, 1) void mlstm_mfma(
    const float* __restrict__ q, const float* __restrict__ k,
    const float* __restrict__ v, const float* __restrict__ ig,
    const float* __restrict__ fg, float* __restrict__ out) {

  __shared__ __align__(16) float q_lds[64 * 64];   // fp32, slot-swizzled
  __shared__ __align__(16) float k_lds[64 * 64];   // fp32, slot-swizzled
  __shared__ __align__(16) char vt_raw[64 * 128];  // V^T bf16, swizzled
  __shared__ __align__(16) char cs_raw[64 * 128];  // C bf16, swizzled
  __shared__ __align__(16) float ea_sh[64];
  __shared__ float eb_sh[64], em_sh[64];

  const int lane = threadIdx.x;
  const int m = lane & 15;   // fragment row/col index
  const int g = lane >> 4;   // fragment k-group
  const size_t cbase = (size_t)blockIdx.x * (L * DH);
  const size_t gb = (size_t)blockIdx.x * L;

  // ======== phase 0: gates, V reg-loads (oldest), then Q/K DMA ===========
  const float fgv = fg[gb + lane];
  const float igv = ig[gb + lane];

  const float4* v4 = (const float4*)(v + cbase);
  float4 vbuf[16];
#pragma unroll
  for (int it = 0; it < 16; ++it) vbuf[it] = v4[it * 64 + lane];

  // Q,K -> LDS DMA. Lane writes LDS float index it*256+lane*4, i.e. row
  // r = it*4 + lane/16, slot = lane&15; source column slot^kkey(r) so that
  // reads at slot (c4 ^ kkey(r)) recover column c4 conflict-free.
  {
    const int rsub = lane >> 4;
    const int slot = lane & 15;
#pragma unroll
    for (int it = 0; it < 16; ++it) {
      const int r = it * 4 + rsub;
      const int coff = r * 64 + ((slot ^ kkey(r)) << 2);
      gload16(q + cbase + coff, &q_lds[it * 256]);
      gload16(k + cbase + coff, &k_lds[it * 256]);
    }
  }

  // ======== gate scan (VALU only; overlaps all memory) ====================
  {
    const float lf = fminf(fgv, 0.f) - log1pf(__expf(-fabsf(fgv)));
    float cum = lf;
#pragma unroll
    for (int o = 1; o < 64; o <<= 1) {
      const float t = __shfl_up(cum, o, 64);
      if (lane >= o) cum += t;
    }
    const float a = igv - cum;
    float b = a;
#pragma unroll
    for (int o = 1; o < 64; o <<= 1) {
      const float t = __shfl_up(b, o, 64);
      if (lane >= o) b = fmaxf(b, t);
    }
    const float bmax = __shfl(b, 63, 64);
    ea_sh[lane] = 0.125f * __expf(a - bmax);  // fold 1/sqrt(DH)
    eb_sh[lane] = __expf(bmax - b);
    em_sh[lane] = __expf(-(b + cum));
  }

  // ======== V^T scatter (waits only V loads — they are the oldest) ========
  {
    unsigned short* vt = (unsigned short*)vt_raw;
#pragma unroll
    for (int it = 0; it < 16; ++it) {
      const int idx = it * 64 + lane;  // float4 index in the chunk
      const int j = idx >> 4;          // time index
      const int d0 = (idx & 15) * 4;   // feature
      vt[swz(d0 + 0, j) >> 1] = bfbits(vbuf[it].x);
      vt[swz(d0 + 1, j) >> 1] = bfbits(vbuf[it].y);
      vt[swz(d0 + 2, j) >> 1] = bfbits(vbuf[it].z);
      vt[swz(d0 + 3, j) >> 1] = bfbits(vbuf[it].w);
    }
  }

  // ======== single drain: all Q/K DMA (and V) complete ====================
  asm volatile("s_waitcnt vmcnt(0)" ::: "memory");

  // ======== Q/K fragments from fp32 LDS (b128 pairs, <=2-way) + cvt =======
  bf16x8 qf[4][2], kf[4][2];
#pragma unroll
  for (int rb = 0; rb < 4; ++rb)
#pragma unroll
    for (int kb = 0; kb < 2; ++kb) {
      const int row = rb * 16 + m;
      const int c4 = kb * 8 + g * 2;
      const int o0 = row * 64 + (((c4 + 0) ^ kkey(row)) << 2);
      const int o1 = row * 64 + (((c4 + 1) ^ kkey(row)) << 2);
      const f32x4 ka = *(const f32x4*)&k_lds[o0];
      const f32x4 kb4 = *(const f32x4*)&k_lds[o1];
      const f32x4 qa = *(const f32x4*)&q_lds[o0];
      const f32x4 qb = *(const f32x4*)&q_lds[o1];
      kf[rb][kb] = bf16x8{tobf(ka[0]), tobf(ka[1]), tobf(ka[2]), tobf(ka[3]),
                          tobf(kb4[0]), tobf(kb4[1]), tobf(kb4[2]), tobf(kb4[3])};
      qf[rb][kb] = bf16x8{tobf(qa[0]), tobf(qa[1]), tobf(qa[2]), tobf(qa[3]),
                          tobf(qb[0]), tobf(qb[1]), tobf(qb[2]), tobf(qb[3])};
    }

  // ======== V^T fragments (issue early; consumed in mm2) ==================
  bf16x8 vfr[4][2];
#pragma unroll
  for (int db = 0; db < 4; ++db)
#pragma unroll
    for (int jb = 0; jb < 2; ++jb)
      vfr[db][jb] =
          *(const bf16x8*)(vt_raw + swz(db * 16 + m, jb * 32 + g * 8));

  // ======== mm1: S^T tiles (only rb <= cb are causal) =====================
  f32x4 st[4][4];
#pragma unroll
  for (int cb = 0; cb < 4; ++cb)
#pragma unroll
    for (int rb = 0; rb < 4; ++rb) {
      if (rb > cb) continue;
      f32x4 acc = {0.f, 0.f, 0.f, 0.f};
      acc = __builtin_amdgcn_mfma_f32_16x16x32_bf16(kf[rb][0], qf[cb][0], acc, 0, 0, 0);
      acc = __builtin_amdgcn_mfma_f32_16x16x32_bf16(kf[rb][1], qf[cb][1], acc, 0, 0, 0);
      st[rb][cb] = acc;
    }

  // ======== gating, row-sum, normalizer; write C (bf16) ===================
  float ea_j[4][4];
#pragma unroll
  for (int rb = 0; rb < 4; ++rb) {
    const float4 ea4 = *(const float4*)&ea_sh[rb * 16 + g * 4];
    ea_j[rb][0] = ea4.x; ea_j[rb][1] = ea4.y;
    ea_j[rb][2] = ea4.z; ea_j[rb][3] = ea4.w;
  }

  float invr[4];
#pragma unroll
  for (int cb = 0; cb < 4; ++cb) {
    const int i = cb * 16 + m;
    const float ebv = eb_sh[i];
    float rs = 0.f;
    const int rbfill = cb | 1;  // zero-fill the jb ranges mm2 will read
#pragma unroll
    for (int rb = 0; rb < 4; ++rb) {
      if (rb > rbfill) continue;
      unsigned long long wp = 0ull;
      if (rb <= cb) {
        float vv[4];
#pragma unroll
        for (int e = 0; e < 4; ++e) {
          const int j = rb * 16 + g * 4 + e;
          vv[e] = (j <= i) ? st[rb][cb][e] * ea_j[rb][e] * ebv : 0.f;
          rs += vv[e];
        }
        wp = pack4(vv[0], vv[1], vv[2], vv[3]);
      }
      *(unsigned long long*)(cs_raw + swz(i, rb * 16 + g * 4)) = wp;
    }
    rs += __shfl_xor(rs, 16, 64);
    rs += __shfl_xor(rs, 32, 64);
    const float n = fmaxf(fabsf(rs), em_sh[i]);
    invr[cb] = 1.f / (n + 1e-6f);
  }

  // ======== mm2 (per-ib): H^T = V^T * C^T, scale + store ===================
#pragma unroll
  for (int ib = 0; ib < 4; ++ib) {
    const int i = ib * 16 + m;
    const bf16x8 c0 = *(const bf16x8*)(cs_raw + swz(i, g * 8));
    f32x4 acc[4];
#pragma unroll
    for (int db = 0; db < 4; ++db) {
      f32x4 z = {0.f, 0.f, 0.f, 0.f};
      acc[db] = __builtin_amdgcn_mfma_f32_16x16x32_bf16(vfr[db][0], c0, z, 0, 0, 0);
    }
    if (ib >= 2) {
      const bf16x8 c1 = *(const bf16x8*)(cs_raw + swz(i, 32 + g * 8));
#pragma unroll
      for (int db = 0; db < 4; ++db)
        acc[db] = __builtin_amdgcn_mfma_f32_16x16x32_bf16(vfr[db][1], c1, acc[db], 0, 0, 0);
    }
    const float iv = invr[ib];
    float* op = out + cbase + i * 64 + g * 4;
#pragma unroll
    for (int db = 0; db < 4; ++db) {
      const f32x4 hv = acc[db];
      *(float4*)(op + db * 16) =
          make_float4(hv[0] * iv, hv[1] * iv, hv[2] * iv, hv[3] * iv);
    }
  }
}

}  // namespace

extern "C" void kernel_launch(void* const* d_in, const int* in_sizes, int n_in,
                              void* d_out, int out_size, void* d_ws,
                              size_t ws_size, hipStream_t stream) {
  const float* q = (const float*)d_in[0];
  const float* k = (const float*)d_in[1];
  const float* v = (const float*)d_in[2];
  const float* ig = (const float*)d_in[3];
  const float* fg = (const float*)d_in[4];
  float* out = (float*)d_out;

  const int total = in_sizes[0];         // B*NH*S*DH
  const int nchunks = total / (L * DH);  // 2048
  mlstm_mfma<<<dim3(nchunks), dim3(64), 0, stream>>>(q, k, v, ig, fg, out);
}